// Round 6
// baseline (231.047 us; speedup 1.0000x reference)
//
#include <hip/hip_runtime.h>
#include <stdint.h>

#define S_LEN 1024
#define DM 1024
#define NH 16
#define DH 64
#define NB 4

typedef unsigned short u16;
typedef __attribute__((ext_vector_type(8))) short short8;
typedef __attribute__((ext_vector_type(4))) float f32x4;
typedef __attribute__((ext_vector_type(4))) unsigned int u32x4;
typedef __attribute__((ext_vector_type(4))) unsigned short u16x4;

// log2(e)/8: QK scale folded with exp2 conversion
#define SCL 0.18033688011112042f

__device__ __forceinline__ u16 f2bf(float f) {
  union { float f; unsigned int u; } c;
  c.f = f;
  unsigned int u = c.u;
  return (u16)((u + 0x7fffu + ((u >> 16) & 1u)) >> 16);
}

// async global->LDS, 16B per lane. LDS dest must be wave-uniform-base + lane*16.
__device__ __forceinline__ void g2l16(const void* g, void* l) {
  __builtin_amdgcn_global_load_lds(
      (const __attribute__((address_space(1))) unsigned int*)(uintptr_t)g,
      (__attribute__((address_space(3))) unsigned int*)(uint32_t)(uintptr_t)l,
      16, 0, 0);
}

// 16-lane-group allreduce on the VALU pipe (DPP): quad_perm xor1, xor2,
// row_ror:4, row_ror:8. Rotate-allreduce; exec must be wave-uniform.
__device__ __forceinline__ float grp16_max(float v) {
  union { float f; int i; } c, o;
  c.f = v; o.i = __builtin_amdgcn_update_dpp(c.i, c.i, 0xB1, 0xF, 0xF, false);
  v = fmaxf(v, o.f);
  c.f = v; o.i = __builtin_amdgcn_update_dpp(c.i, c.i, 0x4E, 0xF, 0xF, false);
  v = fmaxf(v, o.f);
  c.f = v; o.i = __builtin_amdgcn_update_dpp(c.i, c.i, 0x124, 0xF, 0xF, false);
  v = fmaxf(v, o.f);
  c.f = v; o.i = __builtin_amdgcn_update_dpp(c.i, c.i, 0x128, 0xF, 0xF, false);
  v = fmaxf(v, o.f);
  return v;
}
__device__ __forceinline__ float grp16_sum(float v) {
  union { float f; int i; } c, o;
  c.f = v; o.i = __builtin_amdgcn_update_dpp(c.i, c.i, 0xB1, 0xF, 0xF, false);
  v += o.f;
  c.f = v; o.i = __builtin_amdgcn_update_dpp(c.i, c.i, 0x4E, 0xF, 0xF, false);
  v += o.f;
  c.f = v; o.i = __builtin_amdgcn_update_dpp(c.i, c.i, 0x124, 0xF, 0xF, false);
  v += o.f;
  c.f = v; o.i = __builtin_amdgcn_update_dpp(c.i, c.i, 0x128, 0xF, 0xF, false);
  v += o.f;
  return v;
}

// ---------------------------------------------------------------------------
// Kernel 0: fp32 -> bf16 pre-convert of x, Wq, Wk, Wv, Er into workspace.
// ---------------------------------------------------------------------------
__global__ __launch_bounds__(256) void cvt_f32_bf16(
    const float* __restrict__ x, const float* __restrict__ Wq,
    const float* __restrict__ Wk, const float* __restrict__ Wv,
    const float* __restrict__ Er, u16* __restrict__ xb,
    u16* __restrict__ Wqb, u16* __restrict__ Wkb, u16* __restrict__ Wvb,
    u16* __restrict__ Erb) {
  const size_t f = ((size_t)blockIdx.x * 256 + threadIdx.x) * 8;
  const float* src;
  u16* dst;
  size_t off;
  if (f < 4194304) { src = x; dst = xb; off = f; }
  else if (f < 5242880) { src = Wq; dst = Wqb; off = f - 4194304; }
  else if (f < 6291456) { src = Wk; dst = Wkb; off = f - 5242880; }
  else if (f < 7340032) { src = Wv; dst = Wvb; off = f - 6291456; }
  else { src = Er; dst = Erb; off = f - 7340032; }
  const float4 a = *(const float4*)(src + off);
  const float4 b = *(const float4*)(src + off + 4);
  u16 o[8] = {f2bf(a.x), f2bf(a.y), f2bf(a.z), f2bf(a.w),
              f2bf(b.x), f2bf(b.y), f2bf(b.z), f2bf(b.w)};
  *(u32x4*)(dst + off) = *(const u32x4*)o;
}

// ---------------------------------------------------------------------------
// Kernel 1: fused QKV projection (bf16 in, bf16 out).
// z=0 -> Q [B,H,S,dh], z=1 -> K [B,H,S,dh], z=2 -> V transposed [B,H,dh,S]
// 2-phase double-buffered staging (prefetch k+32 before computing k, one
// barrier per iter). Epilogue: operand-SWAPPED MFMA for z!=2 so the 4 acc
// elements per (i,j) are 4 consecutive d -> single 8B store; for z==2 the
// unswapped order gives 4 consecutive s in V^T -> single 8B store.
// (Verified mapping: D-row (fq*4+r) <-> FIRST operand rows, D-col (fr) <->
// second operand rows.)
// ---------------------------------------------------------------------------
__global__ __launch_bounds__(256) void qkv_gemm(
    const u16* __restrict__ x,
    const u16* __restrict__ Wq, const float* __restrict__ bq,
    const u16* __restrict__ Wk, const float* __restrict__ bk,
    const u16* __restrict__ Wv, const float* __restrict__ bv,
    u16* __restrict__ Qo, u16* __restrict__ Ko, u16* __restrict__ Vo) {
  __shared__ __attribute__((aligned(16))) u16 Al[2][128 * 32];
  __shared__ __attribute__((aligned(16))) u16 Bl[2][128 * 32];

  const int tid = threadIdx.x;
  const int lane = tid & 63;
  const int wave = tid >> 6;
  const int z = blockIdx.z;
  const u16* W = (z == 0) ? Wq : (z == 1) ? Wk : Wv;
  const float* bias = (z == 0) ? bq : (z == 1) ? bk : bv;

  const int m0 = blockIdx.y * 128;
  const int n0 = blockIdx.x * 128;

  f32x4 acc[4][4];
  const f32x4 fzero = {0.f, 0.f, 0.f, 0.f};
#pragma unroll
  for (int i = 0; i < 4; i++)
#pragma unroll
    for (int j = 0; j < 4; j++) acc[i][j] = fzero;

  const int srow = tid >> 2;
  const int schunk = tid & 3;
  const u16* gA = x + (size_t)(m0 + srow) * DM + schunk * 8;
  const u16* gB = W + (size_t)(n0 + srow) * DM + schunk * 8;

  const int fr = lane & 15;
  const int fq = lane >> 4;
  const int wr = (wave >> 1) * 64;
  const int wc = (wave & 1) * 64;

  auto stageAB = [&](int k, int bf) {
    g2l16(gA + k, &Al[bf][tid * 8]);
    g2l16(gA + (size_t)64 * DM + k, &Al[bf][2048 + tid * 8]);
    g2l16(gB + k, &Bl[bf][tid * 8]);
    g2l16(gB + (size_t)64 * DM + k, &Bl[bf][2048 + tid * 8]);
  };

  stageAB(0, 0);
  __syncthreads();
  int bf = 0;

  for (int k = 0; k < DM; k += 32) {
    if (k + 32 < DM) stageAB(k + 32, bf ^ 1);  // prefetch next K-step
    short8 a[4], b[4];
#pragma unroll
    for (int i = 0; i < 4; i++)
      a[i] = *(const short8*)&Al[bf][(wr + i * 16 + fr) * 32 + fq * 8];
#pragma unroll
    for (int j = 0; j < 4; j++)
      b[j] = *(const short8*)&Bl[bf][(wc + j * 16 + fr) * 32 + fq * 8];
    if (z == 2) {
#pragma unroll
      for (int i = 0; i < 4; i++)
#pragma unroll
        for (int j = 0; j < 4; j++)
          acc[i][j] = __builtin_amdgcn_mfma_f32_16x16x32_bf16(a[i], b[j],
                                                              acc[i][j], 0, 0, 0);
    } else {
#pragma unroll
      for (int i = 0; i < 4; i++)
#pragma unroll
        for (int j = 0; j < 4; j++)
          acc[i][j] = __builtin_amdgcn_mfma_f32_16x16x32_bf16(b[j], a[i],
                                                              acc[i][j], 0, 0, 0);
    }
    __syncthreads();  // implicit vmcnt(0): prefetch landed; reads done
    bf ^= 1;
  }

  if (z == 2) {
    // unswapped: D-row ~ x-row (s varies over r), D-col ~ W-row (fixed n)
#pragma unroll
    for (int j = 0; j < 4; j++) {
      const int n = n0 + wc + j * 16 + fr;
      const float bsv = bias[n];
      const int h = n >> 6, d = n & (DH - 1);
#pragma unroll
      for (int i = 0; i < 4; i++) {
        const int mb = m0 + wr + i * 16 + fq * 4;
        const int bb = mb >> 10, s = mb & (S_LEN - 1);
        u16x4 o;
#pragma unroll
        for (int r = 0; r < 4; r++) o[r] = f2bf(acc[i][j][r] + bsv);
        *(u16x4*)&Vo[((size_t)(bb * NH + h) * DH + d) * S_LEN + s] = o;
      }
    }
  } else {
    // swapped: D-row ~ W-row (d varies over r), D-col ~ x-row (fixed s)
    u16* O = (z == 0) ? Qo : Ko;
#pragma unroll
    for (int i = 0; i < 4; i++) {
      const int m = m0 + wr + i * 16 + fr;
      const int bb = m >> 10, s = m & (S_LEN - 1);
#pragma unroll
      for (int j = 0; j < 4; j++) {
        const int nb = n0 + wc + j * 16 + fq * 4;
        const float4 b4 = *(const float4*)&bias[nb];
        const int h = nb >> 6, d = nb & (DH - 1);
        u16x4 o;
        o[0] = f2bf(acc[i][j][0] + b4.x);
        o[1] = f2bf(acc[i][j][1] + b4.y);
        o[2] = f2bf(acc[i][j][2] + b4.z);
        o[3] = f2bf(acc[i][j][3] + b4.w);
        *(u16x4*)&O[((size_t)(bb * NH + h) * S_LEN + s) * DH + d] = o;
      }
    }
  }
}

// ---------------------------------------------------------------------------
// Kernel 2: causal flash attention with relative-position (skew) bias.
// r5 structure (1024 blocks x 4 waves, 64-row q-tiles, 40KB LDS, Er ring,
// swizzled K/V/El staging, DPP softmax) + VALU cuts:
//  - softmax in exp2/log2 domain (log2e folded into QK scale),
//  - defer-max (T13): wave-uniform __all skip of the rescale pass,
//  - deferred lrow allreduce: per-lane partials in the loop, one DPP
//    allreduce at the epilogue (alpha is 16-group-uniform, so linearity holds).
// ---------------------------------------------------------------------------
__global__ __launch_bounds__(256, 4) void attn(
    const u16* __restrict__ Q, const u16* __restrict__ K,
    const u16* __restrict__ Vt, const u16* __restrict__ Er,
    float* __restrict__ out) {
  __shared__ __attribute__((aligned(16))) u16 Kl[64 * 64];     // 8KB
  __shared__ __attribute__((aligned(16))) u16 Vl[64 * 64];     // 8KB
  __shared__ __attribute__((aligned(16))) u16 El[128 * 64];    // 16KB ring
  __shared__ __attribute__((aligned(16))) u16 Pl[4][16 * 64];  // 8KB

  const int tid = threadIdx.x;
  const int lane = tid & 63;
  const int w = tid >> 6;  // wave 0..3
  const int bh = blockIdx.y;
  const int b = bh >> 4, h = bh & (NH - 1);
  const int it = ((int)blockIdx.x + bh + ((bh >> 4) << 2)) & 15;
  const int i0 = it * 64;          // this block's 64 q-rows
  const int i0w = i0 + w * 16;     // this wave's 16 q-rows
  const int E0b = S_LEN - 64 - i0;  // Er window base at j0=0

  const u16* Qb = Q + (size_t)bh * S_LEN * DH;
  const char* Kb = (const char*)(K + (size_t)bh * S_LEN * DH);
  const char* Vb = (const char*)(Vt + (size_t)bh * DH * S_LEN);
  const char* Eb = (const char*)Er;
  u16* Pw = Pl[w];

  const int fr = lane & 15;
  const int fq = lane >> 4;
  const f32x4 fzero = {0.f, 0.f, 0.f, 0.f};

  const int r8 = tid >> 3;        // 0..31
  const int ch = (tid & 7) * 16;  // byte chunk within 128B row

  auto stageKV = [&](int j0) {
#pragma unroll
    for (int p = 0; p < 2; p++) {
      const int row = p * 32 + r8;
      const int sw = ch ^ ((row & 7) << 4);
      g2l16(Kb + (size_t)(j0 + row) * 128 + sw, (char*)Kl + row * 128 + ch);
      g2l16(Vb + (size_t)row * 2048 + j0 * 2 + sw, (char*)Vl + row * 128 + ch);
    }
  };
  auto stageEl = [&](int e0, int np) {
    for (int p = 0; p < np; p++) {
      const int e = e0 + p * 32 + r8;
      const int slot = e & 127;
      const int ec = (e > S_LEN - 1) ? (S_LEN - 1) : e;  // masked anyway
      const int sw = ch ^ ((slot & 7) << 4);
      g2l16(Eb + (size_t)ec * 128 + sw, (char*)El + slot * 128 + ch);
    }
  };

  const short8 aq0 = *(const short8*)&Qb[(size_t)(i0w + fr) * DH + fq * 8];
  const short8 aq1 = *(const short8*)&Qb[(size_t)(i0w + fr) * DH + 32 + fq * 8];

  float mrow[4], lp[4];
  f32x4 accO[4];
#pragma unroll
  for (int r = 0; r < 4; r++) { mrow[r] = -3.0e38f; lp[r] = 0.f; }
#pragma unroll
  for (int t = 0; t < 4; t++) accO[t] = fzero;

  f32x4 zzc = fzero;  // carried Er band fragment (prev f=4 -> next f=0)
  const int ksw = (fr & 7) << 4;

  for (int j0 = 0; j0 <= i0; j0 += 64) {
    stageKV(j0);
    if (j0 == 0) stageEl(E0b, 4);
    else stageEl(E0b + j0 + 64, 2);
    __syncthreads();  // implicit vmcnt(0): staging landed

    int tmax = (i0w + 15 - j0) >> 4;
    if (tmax > 3) tmax = 3;

    // ---- S = Q K^T from swizzled LDS
    f32x4 sfr[4];
#pragma unroll
    for (int t = 0; t < 4; t++) sfr[t] = fzero;
    __builtin_amdgcn_s_setprio(1);
#pragma unroll
    for (int t = 0; t < 4; t++)
      if (t <= tmax) {
        const char* kr = (const char*)Kl + (t * 16 + fr) * 128;
        const short8 b0 = *(const short8*)(kr + ((fq * 16) ^ ksw));
        const short8 b1 = *(const short8*)(kr + ((64 + fq * 16) ^ ksw));
        f32x4 z = fzero;
        z = __builtin_amdgcn_mfma_f32_16x16x32_bf16(aq0, b0, z, 0, 0, 0);
        z = __builtin_amdgcn_mfma_f32_16x16x32_bf16(aq1, b1, z, 0, 0, 0);
        sfr[t] = z;
      }
    __builtin_amdgcn_s_setprio(0);

    // ---- banded QEr from the ring; f=0 carried when j0>0
    const int ebs = S_LEN - 16 - i0w + j0;
    f32x4 zz[5];
#pragma unroll
    for (int f = 0; f < 5; f++) zz[f] = fzero;
    const int f0 = (j0 == 0) ? 0 : 1;
#pragma unroll
    for (int f = 0; f < 5; f++)
      if (f >= f0 && f <= tmax + 1) {
        const int slot = ((ebs + f * 16) & 127) + fr;  // no straddle
        const char* er = (const char*)El + slot * 128;
        const short8 b0 = *(const short8*)(er + ((fq * 16) ^ ksw));
        const short8 b1 = *(const short8*)(er + ((64 + fq * 16) ^ ksw));
        f32x4 z = fzero;
        z = __builtin_amdgcn_mfma_f32_16x16x32_bf16(aq0, b0, z, 0, 0, 0);
        z = __builtin_amdgcn_mfma_f32_16x16x32_bf16(aq1, b1, z, 0, 0, 0);
        zz[f] = z;
      }
    if (j0 > 0) zz[0] = zzc;
    zzc = zz[4];

    // ---- in-register skew gather (log2-domain scale folded in)
    float p[4][4];
#pragma unroll
    for (int r = 0; r < 4; r++) {
      const int row = fq * 4 + r;
      const int c = 15 - row + fr;           // 0..30
      const int src = (fq << 4) | (c & 15);  // same row-group, lane c&15
      float sh[5];
#pragma unroll
      for (int f = 0; f < 5; f++) sh[f] = __shfl(zz[f][r], src);
#pragma unroll
      for (int t = 0; t < 4; t++) {
        const float rel = (c < 16) ? sh[t] : sh[t + 1];
        float sv = (sfr[t][r] + rel) * SCL;
        const int jj = j0 + t * 16 + fr;
        const int ii = i0w + row;
        if (jj > ii) sv = -3.0e38f;
        p[t][r] = sv;
      }
    }

    // ---- online softmax (exp2 domain, defer-max, per-lane lrow partials)
    float rm4[4];
    int small = 1;
#pragma unroll
    for (int r = 0; r < 4; r++) {
      float rm = fmaxf(fmaxf(p[0][r], p[1][r]), fmaxf(p[2][r], p[3][r]));
      rm = grp16_max(rm);
      rm4[r] = rm;
      small &= (rm <= mrow[r] + 11.0f) ? 1 : 0;
    }
    if (__all(small)) {
      // deferred: keep old max, no rescale (P bounded by 2^11)
#pragma unroll
      for (int r = 0; r < 4; r++) {
        float rs = 0.f;
#pragma unroll
        for (int t = 0; t < 4; t++) {
          const float e = __builtin_amdgcn_exp2f(p[t][r] - mrow[r]);
          p[t][r] = e;
          rs += e;
        }
        lp[r] += rs;
      }
    } else {
#pragma unroll
      for (int r = 0; r < 4; r++) {
        const float mnew = fmaxf(mrow[r], rm4[r]);
        const float alpha = __builtin_amdgcn_exp2f(mrow[r] - mnew);
        mrow[r] = mnew;
        float rs = 0.f;
#pragma unroll
        for (int t = 0; t < 4; t++) {
          const float e = __builtin_amdgcn_exp2f(p[t][r] - mnew);
          p[t][r] = e;
          rs += e;
        }
        lp[r] = lp[r] * alpha + rs;
#pragma unroll
        for (int t = 0; t < 4; t++) accO[t][r] *= alpha;
      }
    }

    // ---- P transpose, wave-private, XOR-swizzled (stride 64 u16)
#pragma unroll
    for (int t = 0; t < 4; t++)
#pragma unroll
      for (int r = 0; r < 4; r++)
        Pw[(fq * 4 + r) * 64 + (((t ^ fq) << 4) + fr)] = f2bf(p[t][r]);
    __builtin_amdgcn_s_waitcnt(0xC07F);  // lgkmcnt(0): own writes visible

    const int rsw = (fr >> 2) << 4;
    const short8 ap0 = *(const short8*)&Pw[fr * 64 + ((fq * 8) ^ rsw)];
    const short8 ap1 = *(const short8*)&Pw[fr * 64 + ((32 + fq * 8) ^ rsw)];

    // ---- O += P V from swizzled LDS
    __builtin_amdgcn_s_setprio(1);
#pragma unroll
    for (int t = 0; t < 4; t++) {
      const char* vr = (const char*)Vl + (t * 16 + fr) * 128;
      const short8 b0 = *(const short8*)(vr + ((fq * 16) ^ ksw));
      const short8 b1 = *(const short8*)(vr + ((64 + fq * 16) ^ ksw));
      accO[t] =
          __builtin_amdgcn_mfma_f32_16x16x32_bf16(ap0, b0, accO[t], 0, 0, 0);
      accO[t] =
          __builtin_amdgcn_mfma_f32_16x16x32_bf16(ap1, b1, accO[t], 0, 0, 0);
    }
    __builtin_amdgcn_s_setprio(0);

    __syncthreads();  // all reads done before next iter's staging overwrites
  }

  // ---- epilogue: one deferred lrow allreduce, then O / l, write fp32
#pragma unroll
  for (int r = 0; r < 4; r++) {
    const float lr = grp16_sum(lp[r]);
    const float inv = 1.f / lr;
    const int s = i0w + fq * 4 + r;
#pragma unroll
    for (int t = 0; t < 4; t++) {
      const int d = t * 16 + fr;
      out[((size_t)b * S_LEN + s) * DM + h * DH + d] = accO[t][r] * inv;
    }
  }
}

extern "C" void kernel_launch(void* const* d_in, const int* in_sizes, int n_in,
                              void* d_out, int out_size, void* d_ws, size_t ws_size,
                              hipStream_t stream) {
  const float* x = (const float*)d_in[0];
  const float* Wq = (const float*)d_in[1];
  const float* bq = (const float*)d_in[2];
  const float* Wk = (const float*)d_in[3];
  const float* bk = (const float*)d_in[4];
  const float* Wv = (const float*)d_in[5];
  const float* bv = (const float*)d_in[6];
  const float* Er = (const float*)d_in[7];
  float* out = (float*)d_out;

  const size_t per = (size_t)NB * NH * S_LEN * DH;  // 4M elems
  u16* Qw = (u16*)d_ws;
  u16* Kw = Qw + per;
  u16* Vw = Kw + per;
  u16* xb = Vw + per;
  u16* Wqb = xb + per;
  u16* Wkb = Wqb + (size_t)DM * DM;
  u16* Wvb = Wkb + (size_t)DM * DM;
  u16* Erb = Wvb + (size_t)DM * DM;

  cvt_f32_bf16<<<3616, 256, 0, stream>>>(x, Wq, Wk, Wv, Er, xb, Wqb, Wkb, Wvb,
                                         Erb);
  dim3 g1(DM / 128, (NB * S_LEN) / 128, 3);
  qkv_gemm<<<g1, dim3(256), 0, stream>>>(xb, Wqb, bq, Wkb, bk, Wvb, bv, Qw, Kw,
                                         Vw);
  dim3 g2(16, NB * NH);
  attn<<<g2, dim3(256), 0, stream>>>(Qw, Kw, Vw, Erb, out);
}

// Round 7
// 185.494 us; speedup vs baseline: 1.2456x; 1.2456x over previous
//
#include <hip/hip_runtime.h>
#include <stdint.h>

#define S_LEN 1024
#define DM 1024
#define NH 16
#define DH 64
#define NB 4

typedef unsigned short u16;
typedef __attribute__((ext_vector_type(8))) short short8;
typedef __attribute__((ext_vector_type(4))) float f32x4;
typedef __attribute__((ext_vector_type(4))) unsigned int u32x4;
typedef __attribute__((ext_vector_type(4))) unsigned short u16x4;

__device__ __forceinline__ u16 f2bf(float f) {
  union { float f; unsigned int u; } c;
  c.f = f;
  unsigned int u = c.u;
  return (u16)((u + 0x7fffu + ((u >> 16) & 1u)) >> 16);
}

// async global->LDS, 16B per lane. LDS dest must be wave-uniform-base + lane*16.
__device__ __forceinline__ void g2l16(const void* g, void* l) {
  __builtin_amdgcn_global_load_lds(
      (const __attribute__((address_space(1))) unsigned int*)(uintptr_t)g,
      (__attribute__((address_space(3))) unsigned int*)(uint32_t)(uintptr_t)l,
      16, 0, 0);
}

// 16-lane-group allreduce on the VALU pipe (DPP): quad_perm xor1, xor2,
// row_ror:4, row_ror:8. Rotate-allreduce; exec must be wave-uniform.
__device__ __forceinline__ float grp16_max(float v) {
  union { float f; int i; } c, o;
  c.f = v; o.i = __builtin_amdgcn_update_dpp(c.i, c.i, 0xB1, 0xF, 0xF, false);
  v = fmaxf(v, o.f);
  c.f = v; o.i = __builtin_amdgcn_update_dpp(c.i, c.i, 0x4E, 0xF, 0xF, false);
  v = fmaxf(v, o.f);
  c.f = v; o.i = __builtin_amdgcn_update_dpp(c.i, c.i, 0x124, 0xF, 0xF, false);
  v = fmaxf(v, o.f);
  c.f = v; o.i = __builtin_amdgcn_update_dpp(c.i, c.i, 0x128, 0xF, 0xF, false);
  v = fmaxf(v, o.f);
  return v;
}
__device__ __forceinline__ float grp16_sum(float v) {
  union { float f; int i; } c, o;
  c.f = v; o.i = __builtin_amdgcn_update_dpp(c.i, c.i, 0xB1, 0xF, 0xF, false);
  v += o.f;
  c.f = v; o.i = __builtin_amdgcn_update_dpp(c.i, c.i, 0x4E, 0xF, 0xF, false);
  v += o.f;
  c.f = v; o.i = __builtin_amdgcn_update_dpp(c.i, c.i, 0x124, 0xF, 0xF, false);
  v += o.f;
  c.f = v; o.i = __builtin_amdgcn_update_dpp(c.i, c.i, 0x128, 0xF, 0xF, false);
  v += o.f;
  return v;
}

// ---------------------------------------------------------------------------
// Kernel 0: fp32 -> bf16 pre-convert of x, Wq, Wk, Wv, Er into workspace.
// ---------------------------------------------------------------------------
__global__ __launch_bounds__(256) void cvt_f32_bf16(
    const float* __restrict__ x, const float* __restrict__ Wq,
    const float* __restrict__ Wk, const float* __restrict__ Wv,
    const float* __restrict__ Er, u16* __restrict__ xb,
    u16* __restrict__ Wqb, u16* __restrict__ Wkb, u16* __restrict__ Wvb,
    u16* __restrict__ Erb) {
  const size_t f = ((size_t)blockIdx.x * 256 + threadIdx.x) * 8;
  const float* src;
  u16* dst;
  size_t off;
  if (f < 4194304) { src = x; dst = xb; off = f; }
  else if (f < 5242880) { src = Wq; dst = Wqb; off = f - 4194304; }
  else if (f < 6291456) { src = Wk; dst = Wkb; off = f - 5242880; }
  else if (f < 7340032) { src = Wv; dst = Wvb; off = f - 6291456; }
  else { src = Er; dst = Erb; off = f - 7340032; }
  const float4 a = *(const float4*)(src + off);
  const float4 b = *(const float4*)(src + off + 4);
  u16 o[8] = {f2bf(a.x), f2bf(a.y), f2bf(a.z), f2bf(a.w),
              f2bf(b.x), f2bf(b.y), f2bf(b.z), f2bf(b.w)};
  *(u32x4*)(dst + off) = *(const u32x4*)o;
}

// ---------------------------------------------------------------------------
// Kernel 1: fused QKV projection (bf16 in, bf16 out). r5 structure (single
// buffer, 2 barriers/iter). ONLY change vs r5: z==2 (V^T) epilogue writes
// u16x4 (4 consecutive s) instead of 4 scalar 2B stores -> 4x fewer write
// transactions on the 2KB-stride scatter path.
// ---------------------------------------------------------------------------
__global__ __launch_bounds__(256) void qkv_gemm(
    const u16* __restrict__ x,
    const u16* __restrict__ Wq, const float* __restrict__ bq,
    const u16* __restrict__ Wk, const float* __restrict__ bk,
    const u16* __restrict__ Wv, const float* __restrict__ bv,
    u16* __restrict__ Qo, u16* __restrict__ Ko, u16* __restrict__ Vo) {
  __shared__ __attribute__((aligned(16))) u16 Al[128 * 32];
  __shared__ __attribute__((aligned(16))) u16 Bl[128 * 32];

  const int tid = threadIdx.x;
  const int lane = tid & 63;
  const int wave = tid >> 6;
  const int z = blockIdx.z;
  const u16* W = (z == 0) ? Wq : (z == 1) ? Wk : Wv;
  const float* bias = (z == 0) ? bq : (z == 1) ? bk : bv;

  const int m0 = blockIdx.y * 128;
  const int n0 = blockIdx.x * 128;

  f32x4 acc[4][4];
  const f32x4 fzero = {0.f, 0.f, 0.f, 0.f};
#pragma unroll
  for (int i = 0; i < 4; i++)
#pragma unroll
    for (int j = 0; j < 4; j++) acc[i][j] = fzero;

  const int srow = tid >> 2;
  const int schunk = tid & 3;
  const u16* gA = x + (size_t)(m0 + srow) * DM + schunk * 8;
  const u16* gB = W + (size_t)(n0 + srow) * DM + schunk * 8;

  const int fr = lane & 15;
  const int fq = lane >> 4;
  const int wr = (wave >> 1) * 64;
  const int wc = (wave & 1) * 64;

  for (int k = 0; k < DM; k += 32) {
    g2l16(gA + k, &Al[tid * 8]);
    g2l16(gA + (size_t)64 * DM + k, &Al[2048 + tid * 8]);
    g2l16(gB + k, &Bl[tid * 8]);
    g2l16(gB + (size_t)64 * DM + k, &Bl[2048 + tid * 8]);
    __syncthreads();
    short8 a[4], b[4];
#pragma unroll
    for (int i = 0; i < 4; i++)
      a[i] = *(const short8*)&Al[(wr + i * 16 + fr) * 32 + fq * 8];
#pragma unroll
    for (int j = 0; j < 4; j++)
      b[j] = *(const short8*)&Bl[(wc + j * 16 + fr) * 32 + fq * 8];
#pragma unroll
    for (int i = 0; i < 4; i++)
#pragma unroll
      for (int j = 0; j < 4; j++)
        acc[i][j] =
            __builtin_amdgcn_mfma_f32_16x16x32_bf16(a[i], b[j], acc[i][j], 0, 0, 0);
    __syncthreads();
  }

#pragma unroll
  for (int j = 0; j < 4; j++) {
    const int n = n0 + wc + j * 16 + fr;
    const float bsv = bias[n];
    const int h = n >> 6, d = n & (DH - 1);
#pragma unroll
    for (int i = 0; i < 4; i++) {
      const int mb = m0 + wr + i * 16 + fq * 4;
      const int bb = mb >> 10, s = mb & (S_LEN - 1);
      if (z == 2) {
        // 4 consecutive s -> one 8B store into V^T
        u16x4 o;
#pragma unroll
        for (int r = 0; r < 4; r++) o[r] = f2bf(acc[i][j][r] + bsv);
        *(u16x4*)&Vo[((size_t)(bb * NH + h) * DH + d) * S_LEN + s] = o;
      } else if (z == 1) {
#pragma unroll
        for (int r = 0; r < 4; r++)
          Ko[((size_t)(bb * NH + h) * S_LEN + s + r) * DH + d] =
              f2bf(acc[i][j][r] + bsv);
      } else {
#pragma unroll
        for (int r = 0; r < 4; r++)
          Qo[((size_t)(bb * NH + h) * S_LEN + s + r) * DH + d] =
              f2bf(acc[i][j][r] + bsv);
      }
    }
  }
}

// ---------------------------------------------------------------------------
// Kernel 2: causal flash attention with relative-position (skew) bias.
// Exact r5 structure (1024 blocks x 4 waves, 64-row q-tiles, 40KB LDS, Er
// ring, swizzled K/V/El staging, DPP softmax). ONLY change vs r5: lrow kept
// as per-lane partials (alpha is 16-group-uniform -> linear), one DPP
// allreduce at the epilogue. Straight-line softmax, no branches.
// ---------------------------------------------------------------------------
__global__ __launch_bounds__(256, 4) void attn(
    const u16* __restrict__ Q, const u16* __restrict__ K,
    const u16* __restrict__ Vt, const u16* __restrict__ Er,
    float* __restrict__ out) {
  __shared__ __attribute__((aligned(16))) u16 Kl[64 * 64];     // 8KB
  __shared__ __attribute__((aligned(16))) u16 Vl[64 * 64];     // 8KB
  __shared__ __attribute__((aligned(16))) u16 El[128 * 64];    // 16KB ring
  __shared__ __attribute__((aligned(16))) u16 Pl[4][16 * 64];  // 8KB

  const int tid = threadIdx.x;
  const int lane = tid & 63;
  const int w = tid >> 6;  // wave 0..3
  const int bh = blockIdx.y;
  const int b = bh >> 4, h = bh & (NH - 1);
  const int it = ((int)blockIdx.x + bh + ((bh >> 4) << 2)) & 15;
  const int i0 = it * 64;           // this block's 64 q-rows
  const int i0w = i0 + w * 16;      // this wave's 16 q-rows
  const int E0b = S_LEN - 64 - i0;  // Er window base at j0=0

  const u16* Qb = Q + (size_t)bh * S_LEN * DH;
  const char* Kb = (const char*)(K + (size_t)bh * S_LEN * DH);
  const char* Vb = (const char*)(Vt + (size_t)bh * DH * S_LEN);
  const char* Eb = (const char*)Er;
  u16* Pw = Pl[w];

  const int fr = lane & 15;
  const int fq = lane >> 4;
  const f32x4 fzero = {0.f, 0.f, 0.f, 0.f};

  const int r8 = tid >> 3;        // 0..31
  const int ch = (tid & 7) * 16;  // byte chunk within 128B row

  auto stageKV = [&](int j0) {
#pragma unroll
    for (int p = 0; p < 2; p++) {
      const int row = p * 32 + r8;
      const int sw = ch ^ ((row & 7) << 4);
      g2l16(Kb + (size_t)(j0 + row) * 128 + sw, (char*)Kl + row * 128 + ch);
      g2l16(Vb + (size_t)row * 2048 + j0 * 2 + sw, (char*)Vl + row * 128 + ch);
    }
  };
  auto stageEl = [&](int e0, int np) {
    for (int p = 0; p < np; p++) {
      const int e = e0 + p * 32 + r8;
      const int slot = e & 127;
      const int ec = (e > S_LEN - 1) ? (S_LEN - 1) : e;  // masked anyway
      const int sw = ch ^ ((slot & 7) << 4);
      g2l16(Eb + (size_t)ec * 128 + sw, (char*)El + slot * 128 + ch);
    }
  };

  const short8 aq0 = *(const short8*)&Qb[(size_t)(i0w + fr) * DH + fq * 8];
  const short8 aq1 = *(const short8*)&Qb[(size_t)(i0w + fr) * DH + 32 + fq * 8];

  float mrow[4], lp[4];
  f32x4 accO[4];
#pragma unroll
  for (int r = 0; r < 4; r++) { mrow[r] = -3.0e38f; lp[r] = 0.f; }
#pragma unroll
  for (int t = 0; t < 4; t++) accO[t] = fzero;

  f32x4 zzc = fzero;  // carried Er band fragment (prev f=4 -> next f=0)
  const int ksw = (fr & 7) << 4;

  for (int j0 = 0; j0 <= i0; j0 += 64) {
    stageKV(j0);
    if (j0 == 0) stageEl(E0b, 4);
    else stageEl(E0b + j0 + 64, 2);
    __syncthreads();  // implicit vmcnt(0): staging landed

    int tmax = (i0w + 15 - j0) >> 4;
    if (tmax > 3) tmax = 3;

    // ---- S = Q K^T from swizzled LDS
    f32x4 sfr[4];
#pragma unroll
    for (int t = 0; t < 4; t++) sfr[t] = fzero;
    __builtin_amdgcn_s_setprio(1);
#pragma unroll
    for (int t = 0; t < 4; t++)
      if (t <= tmax) {
        const char* kr = (const char*)Kl + (t * 16 + fr) * 128;
        const short8 b0 = *(const short8*)(kr + ((fq * 16) ^ ksw));
        const short8 b1 = *(const short8*)(kr + ((64 + fq * 16) ^ ksw));
        f32x4 z = fzero;
        z = __builtin_amdgcn_mfma_f32_16x16x32_bf16(aq0, b0, z, 0, 0, 0);
        z = __builtin_amdgcn_mfma_f32_16x16x32_bf16(aq1, b1, z, 0, 0, 0);
        sfr[t] = z;
      }
    __builtin_amdgcn_s_setprio(0);

    // ---- banded QEr from the ring; f=0 carried when j0>0
    const int ebs = S_LEN - 16 - i0w + j0;
    f32x4 zz[5];
#pragma unroll
    for (int f = 0; f < 5; f++) zz[f] = fzero;
    const int f0 = (j0 == 0) ? 0 : 1;
#pragma unroll
    for (int f = 0; f < 5; f++)
      if (f >= f0 && f <= tmax + 1) {
        const int slot = ((ebs + f * 16) & 127) + fr;  // no straddle
        const char* er = (const char*)El + slot * 128;
        const short8 b0 = *(const short8*)(er + ((fq * 16) ^ ksw));
        const short8 b1 = *(const short8*)(er + ((64 + fq * 16) ^ ksw));
        f32x4 z = fzero;
        z = __builtin_amdgcn_mfma_f32_16x16x32_bf16(aq0, b0, z, 0, 0, 0);
        z = __builtin_amdgcn_mfma_f32_16x16x32_bf16(aq1, b1, z, 0, 0, 0);
        zz[f] = z;
      }
    if (j0 > 0) zz[0] = zzc;
    zzc = zz[4];

    // ---- in-register skew gather: rel[t][r] = band col (15-row+fr)+16t
    float p[4][4];
#pragma unroll
    for (int r = 0; r < 4; r++) {
      const int row = fq * 4 + r;
      const int c = 15 - row + fr;           // 0..30
      const int src = (fq << 4) | (c & 15);  // same row-group, lane c&15
      float sh[5];
#pragma unroll
      for (int f = 0; f < 5; f++) sh[f] = __shfl(zz[f][r], src);
#pragma unroll
      for (int t = 0; t < 4; t++) {
        const float rel = (c < 16) ? sh[t] : sh[t + 1];
        float sv = (sfr[t][r] + rel) * 0.125f;
        const int jj = j0 + t * 16 + fr;
        const int ii = i0w + row;
        if (jj > ii) sv = -3.0e38f;
        p[t][r] = sv;
      }
    }

    // ---- online softmax (DPP max; lrow kept as per-lane partials)
#pragma unroll
    for (int r = 0; r < 4; r++) {
      float rm = fmaxf(fmaxf(p[0][r], p[1][r]), fmaxf(p[2][r], p[3][r]));
      rm = grp16_max(rm);
      const float mnew = fmaxf(mrow[r], rm);
      const float alpha = __expf(mrow[r] - mnew);
      mrow[r] = mnew;
      float rs = 0.f;
#pragma unroll
      for (int t = 0; t < 4; t++) {
        const float e = __expf(p[t][r] - mnew);
        p[t][r] = e;
        rs += e;
      }
      lp[r] = lp[r] * alpha + rs;  // per-lane partial; allreduce at epilogue
#pragma unroll
      for (int t = 0; t < 4; t++) accO[t][r] *= alpha;
    }

    // ---- P transpose, wave-private, XOR-swizzled (stride 64 u16)
#pragma unroll
    for (int t = 0; t < 4; t++)
#pragma unroll
      for (int r = 0; r < 4; r++)
        Pw[(fq * 4 + r) * 64 + (((t ^ fq) << 4) + fr)] = f2bf(p[t][r]);
    __builtin_amdgcn_s_waitcnt(0xC07F);  // lgkmcnt(0): own writes visible

    const int rsw = (fr >> 2) << 4;
    const short8 ap0 = *(const short8*)&Pw[fr * 64 + ((fq * 8) ^ rsw)];
    const short8 ap1 = *(const short8*)&Pw[fr * 64 + ((32 + fq * 8) ^ rsw)];

    // ---- O += P V from swizzled LDS
    __builtin_amdgcn_s_setprio(1);
#pragma unroll
    for (int t = 0; t < 4; t++) {
      const char* vr = (const char*)Vl + (t * 16 + fr) * 128;
      const short8 b0 = *(const short8*)(vr + ((fq * 16) ^ ksw));
      const short8 b1 = *(const short8*)(vr + ((64 + fq * 16) ^ ksw));
      accO[t] =
          __builtin_amdgcn_mfma_f32_16x16x32_bf16(ap0, b0, accO[t], 0, 0, 0);
      accO[t] =
          __builtin_amdgcn_mfma_f32_16x16x32_bf16(ap1, b1, accO[t], 0, 0, 0);
    }
    __builtin_amdgcn_s_setprio(0);

    __syncthreads();  // all reads done before next iter's staging overwrites
  }

  // ---- epilogue: one deferred lrow allreduce, then O / l, write fp32
#pragma unroll
  for (int r = 0; r < 4; r++) {
    const float lr = grp16_sum(lp[r]);
    const float inv = 1.f / lr;
    const int s = i0w + fq * 4 + r;
#pragma unroll
    for (int t = 0; t < 4; t++) {
      const int d = t * 16 + fr;
      out[((size_t)b * S_LEN + s) * DM + h * DH + d] = accO[t][r] * inv;
    }
  }
}

extern "C" void kernel_launch(void* const* d_in, const int* in_sizes, int n_in,
                              void* d_out, int out_size, void* d_ws, size_t ws_size,
                              hipStream_t stream) {
  const float* x = (const float*)d_in[0];
  const float* Wq = (const float*)d_in[1];
  const float* bq = (const float*)d_in[2];
  const float* Wk = (const float*)d_in[3];
  const float* bk = (const float*)d_in[4];
  const float* Wv = (const float*)d_in[5];
  const float* bv = (const float*)d_in[6];
  const float* Er = (const float*)d_in[7];
  float* out = (float*)d_out;

  const size_t per = (size_t)NB * NH * S_LEN * DH;  // 4M elems
  u16* Qw = (u16*)d_ws;
  u16* Kw = Qw + per;
  u16* Vw = Kw + per;
  u16* xb = Vw + per;
  u16* Wqb = xb + per;
  u16* Wkb = Wqb + (size_t)DM * DM;
  u16* Wvb = Wkb + (size_t)DM * DM;
  u16* Erb = Wvb + (size_t)DM * DM;

  cvt_f32_bf16<<<3616, 256, 0, stream>>>(x, Wq, Wk, Wv, Er, xb, Wqb, Wkb, Wvb,
                                         Erb);
  dim3 g1(DM / 128, (NB * S_LEN) / 128, 3);
  qkv_gemm<<<g1, dim3(256), 0, stream>>>(xb, Wqb, bq, Wkb, bk, Wvb, bv, Qw, Kw,
                                         Vw);
  dim3 g2(16, NB * NH);
  attn<<<g2, dim3(256), 0, stream>>>(Qw, Kw, Vw, Erb, out);
}

// Round 8
// 175.764 us; speedup vs baseline: 1.3145x; 1.0554x over previous
//
#include <hip/hip_runtime.h>
#include <stdint.h>

#define S_LEN 1024
#define DM 1024
#define NH 16
#define DH 64
#define NB 4

typedef unsigned short u16;
typedef __attribute__((ext_vector_type(8))) short short8;
typedef __attribute__((ext_vector_type(4))) float f32x4;
typedef __attribute__((ext_vector_type(4))) unsigned int u32x4;
typedef __attribute__((ext_vector_type(4))) unsigned short u16x4;

__device__ __forceinline__ u16 f2bf(float f) {
  union { float f; unsigned int u; } c;
  c.f = f;
  unsigned int u = c.u;
  return (u16)((u + 0x7fffu + ((u >> 16) & 1u)) >> 16);
}

// async global->LDS, 16B per lane. LDS dest must be wave-uniform-base + lane*16.
__device__ __forceinline__ void g2l16(const void* g, void* l) {
  __builtin_amdgcn_global_load_lds(
      (const __attribute__((address_space(1))) unsigned int*)(uintptr_t)g,
      (__attribute__((address_space(3))) unsigned int*)(uint32_t)(uintptr_t)l,
      16, 0, 0);
}

// 16-lane-group allreduce on the VALU pipe (DPP): quad_perm xor1, xor2,
// row_ror:4, row_ror:8. Rotate-allreduce; exec must be wave-uniform.
__device__ __forceinline__ float grp16_max(float v) {
  union { float f; int i; } c, o;
  c.f = v; o.i = __builtin_amdgcn_update_dpp(c.i, c.i, 0xB1, 0xF, 0xF, false);
  v = fmaxf(v, o.f);
  c.f = v; o.i = __builtin_amdgcn_update_dpp(c.i, c.i, 0x4E, 0xF, 0xF, false);
  v = fmaxf(v, o.f);
  c.f = v; o.i = __builtin_amdgcn_update_dpp(c.i, c.i, 0x124, 0xF, 0xF, false);
  v = fmaxf(v, o.f);
  c.f = v; o.i = __builtin_amdgcn_update_dpp(c.i, c.i, 0x128, 0xF, 0xF, false);
  v = fmaxf(v, o.f);
  return v;
}
__device__ __forceinline__ float grp16_sum(float v) {
  union { float f; int i; } c, o;
  c.f = v; o.i = __builtin_amdgcn_update_dpp(c.i, c.i, 0xB1, 0xF, 0xF, false);
  v += o.f;
  c.f = v; o.i = __builtin_amdgcn_update_dpp(c.i, c.i, 0x4E, 0xF, 0xF, false);
  v += o.f;
  c.f = v; o.i = __builtin_amdgcn_update_dpp(c.i, c.i, 0x124, 0xF, 0xF, false);
  v += o.f;
  c.f = v; o.i = __builtin_amdgcn_update_dpp(c.i, c.i, 0x128, 0xF, 0xF, false);
  v += o.f;
  return v;
}

// ---------------------------------------------------------------------------
// Kernel 0: fp32 -> bf16 pre-convert of x, Wq, Wk, Wv, Er into workspace.
// ---------------------------------------------------------------------------
__global__ __launch_bounds__(256) void cvt_f32_bf16(
    const float* __restrict__ x, const float* __restrict__ Wq,
    const float* __restrict__ Wk, const float* __restrict__ Wv,
    const float* __restrict__ Er, u16* __restrict__ xb,
    u16* __restrict__ Wqb, u16* __restrict__ Wkb, u16* __restrict__ Wvb,
    u16* __restrict__ Erb) {
  const size_t f = ((size_t)blockIdx.x * 256 + threadIdx.x) * 8;
  const float* src;
  u16* dst;
  size_t off;
  if (f < 4194304) { src = x; dst = xb; off = f; }
  else if (f < 5242880) { src = Wq; dst = Wqb; off = f - 4194304; }
  else if (f < 6291456) { src = Wk; dst = Wkb; off = f - 5242880; }
  else if (f < 7340032) { src = Wv; dst = Wvb; off = f - 6291456; }
  else { src = Er; dst = Erb; off = f - 7340032; }
  const float4 a = *(const float4*)(src + off);
  const float4 b = *(const float4*)(src + off + 4);
  u16 o[8] = {f2bf(a.x), f2bf(a.y), f2bf(a.z), f2bf(a.w),
              f2bf(b.x), f2bf(b.y), f2bf(b.z), f2bf(b.w)};
  *(u32x4*)(dst + off) = *(const u32x4*)o;
}

// ---------------------------------------------------------------------------
// Kernel 1: fused QKV projection. r7 structure + bijective chunked XCD
// swizzle: HW block o lands on XCD o&7 (round-robin); remap so each XCD
// processes a CONTIGUOUS (z,m,n) range -> each x m-panel is fetched by one
// XCD per z instead of all eight (measured 68.7MB fetch ~= 8x x-scatter).
// ---------------------------------------------------------------------------
__global__ __launch_bounds__(256) void qkv_gemm(
    const u16* __restrict__ x,
    const u16* __restrict__ Wq, const float* __restrict__ bq,
    const u16* __restrict__ Wk, const float* __restrict__ bk,
    const u16* __restrict__ Wv, const float* __restrict__ bv,
    u16* __restrict__ Qo, u16* __restrict__ Ko, u16* __restrict__ Vo) {
  __shared__ __attribute__((aligned(16))) u16 Al[128 * 32];
  __shared__ __attribute__((aligned(16))) u16 Bl[128 * 32];

  const int tid = threadIdx.x;
  const int lane = tid & 63;
  const int wave = tid >> 6;

  // ---- XCD-chunked remap (768 blocks, 768%8==0 -> simple bijection)
  const int o =
      ((int)blockIdx.z * gridDim.y + blockIdx.y) * gridDim.x + blockIdx.x;
  const int swz = (o & 7) * 96 + (o >> 3);
  const int z = swz >> 8;            // 0..2
  const int rem = swz & 255;
  const int m0 = (rem >> 3) * 128;   // 32 m-tiles
  const int n0 = (rem & 7) * 128;    // 8 n-tiles

  const u16* W = (z == 0) ? Wq : (z == 1) ? Wk : Wv;
  const float* bias = (z == 0) ? bq : (z == 1) ? bk : bv;

  f32x4 acc[4][4];
  const f32x4 fzero = {0.f, 0.f, 0.f, 0.f};
#pragma unroll
  for (int i = 0; i < 4; i++)
#pragma unroll
    for (int j = 0; j < 4; j++) acc[i][j] = fzero;

  const int srow = tid >> 2;
  const int schunk = tid & 3;
  const u16* gA = x + (size_t)(m0 + srow) * DM + schunk * 8;
  const u16* gB = W + (size_t)(n0 + srow) * DM + schunk * 8;

  const int fr = lane & 15;
  const int fq = lane >> 4;
  const int wr = (wave >> 1) * 64;
  const int wc = (wave & 1) * 64;

  for (int k = 0; k < DM; k += 32) {
    g2l16(gA + k, &Al[tid * 8]);
    g2l16(gA + (size_t)64 * DM + k, &Al[2048 + tid * 8]);
    g2l16(gB + k, &Bl[tid * 8]);
    g2l16(gB + (size_t)64 * DM + k, &Bl[2048 + tid * 8]);
    __syncthreads();
    short8 a[4], b[4];
#pragma unroll
    for (int i = 0; i < 4; i++)
      a[i] = *(const short8*)&Al[(wr + i * 16 + fr) * 32 + fq * 8];
#pragma unroll
    for (int j = 0; j < 4; j++)
      b[j] = *(const short8*)&Bl[(wc + j * 16 + fr) * 32 + fq * 8];
#pragma unroll
    for (int i = 0; i < 4; i++)
#pragma unroll
      for (int j = 0; j < 4; j++)
        acc[i][j] =
            __builtin_amdgcn_mfma_f32_16x16x32_bf16(a[i], b[j], acc[i][j], 0, 0, 0);
    __syncthreads();
  }

#pragma unroll
  for (int j = 0; j < 4; j++) {
    const int n = n0 + wc + j * 16 + fr;
    const float bsv = bias[n];
    const int h = n >> 6, d = n & (DH - 1);
#pragma unroll
    for (int i = 0; i < 4; i++) {
      const int mb = m0 + wr + i * 16 + fq * 4;
      const int bb = mb >> 10, s = mb & (S_LEN - 1);
      if (z == 2) {
        // 4 consecutive s -> one 8B store into V^T
        u16x4 ov;
#pragma unroll
        for (int r = 0; r < 4; r++) ov[r] = f2bf(acc[i][j][r] + bsv);
        *(u16x4*)&Vo[((size_t)(bb * NH + h) * DH + d) * S_LEN + s] = ov;
      } else if (z == 1) {
#pragma unroll
        for (int r = 0; r < 4; r++)
          Ko[((size_t)(bb * NH + h) * S_LEN + s + r) * DH + d] =
              f2bf(acc[i][j][r] + bsv);
      } else {
#pragma unroll
        for (int r = 0; r < 4; r++)
          Qo[((size_t)(bb * NH + h) * S_LEN + s + r) * DH + d] =
              f2bf(acc[i][j][r] + bsv);
      }
    }
  }
}

// ---------------------------------------------------------------------------
// Kernel 2: causal flash attention with relative-position (skew) bias.
// 1-barrier pipelined 8-wave structure:
//  - 512 blocks x 8 waves, 128-row i-tiles, heavy/light pairing (r2 skeleton,
//    16 waves/CU at 80KB LDS -> 2 blocks/CU).
//  - K/V double-buffered; El is a 256-row mod-256 ring. Prefetch for iter
//    j0+64 issues at the TOP of iter j0 (K/V into buf^1, fresh 64 Er rows
//    into ring slots provably disjoint from this iter's 192-row window:
//    [E0..E0+255] spans exactly 256 rows -> mod-256 images partition).
//  - ONE __syncthreads per iter: its implicit vmcnt(0) drains the prefetch
//    issued ~600cy earlier (hidden under QK/Er/softmax/PV compute).
//  - All verified micro-opts kept: (row&7)<<4 swizzled staging+reads, DPP
//    softmax with deferred-lrow partials, register-carried Er f=4->f=0,
//    per-wave diagonal t-skip, XOR-swizzled P transpose.
// ---------------------------------------------------------------------------
__global__ __launch_bounds__(512, 4) void attn(
    const u16* __restrict__ Q, const u16* __restrict__ K,
    const u16* __restrict__ Vt, const u16* __restrict__ Er,
    float* __restrict__ out) {
  __shared__ __attribute__((aligned(16))) u16 Kl[2][64 * 64];  // 16KB
  __shared__ __attribute__((aligned(16))) u16 Vl[2][64 * 64];  // 16KB
  __shared__ __attribute__((aligned(16))) u16 El[256 * 64];    // 32KB ring
  __shared__ __attribute__((aligned(16))) u16 Pl[8][16 * 64];  // 16KB

  const int tid = threadIdx.x;
  const int lane = tid & 63;
  const int w = tid >> 6;  // wave 0..7
  const int bh = blockIdx.y;
  const int b = bh >> 4, h = bh & (NH - 1);
  // pair heavy i-tiles with light ones across the 2 scheduling rounds
  const int it = (bh < 32) ? (int)blockIdx.x : 7 - (int)blockIdx.x;
  const int i0 = it * 128;
  const int jmax = i0 + 64;
  const int i0w = i0 + w * 16;       // this wave's 16 q-rows
  const int E0b = S_LEN - 128 - i0;  // Er window base at j0=0 (>=0, mult 64)

  const u16* Qb = Q + (size_t)bh * S_LEN * DH;
  const char* Kb = (const char*)(K + (size_t)bh * S_LEN * DH);
  const char* Vb = (const char*)(Vt + (size_t)bh * DH * S_LEN);
  const char* Eb = (const char*)Er;
  u16* Pw = Pl[w];

  const int fr = lane & 15;
  const int fq = lane >> 4;
  const f32x4 fzero = {0.f, 0.f, 0.f, 0.f};

  // staging: 512 threads cover 64 rows x 128B per pass
  const int r0 = tid >> 3;        // row 0..63
  const int ch = (tid & 7) * 16;  // byte chunk within 128B row

  auto stageKV = [&](int j0, int bf) {
    const int sw = ch ^ ((r0 & 7) << 4);
    g2l16(Kb + (size_t)(j0 + r0) * 128 + sw, (char*)&Kl[bf][0] + r0 * 128 + ch);
    g2l16(Vb + (size_t)r0 * 2048 + j0 * 2 + sw,
          (char*)&Vl[bf][0] + r0 * 128 + ch);
  };
  // Er rows [e0, e0+64*np) into ring slots e&255 (e0 mult of 64 -> no
  // straddle; rows >1023 clamp, they only feed masked positions).
  auto stageEl = [&](int e0, int np) {
    for (int p = 0; p < np; p++) {
      const int e = e0 + p * 64 + r0;
      const int slot = e & 255;
      const int ec = (e > S_LEN - 1) ? (S_LEN - 1) : e;
      const int sw = ch ^ ((slot & 7) << 4);
      g2l16(Eb + (size_t)ec * 128 + sw, (char*)El + slot * 128 + ch);
    }
  };

  const short8 aq0 = *(const short8*)&Qb[(size_t)(i0w + fr) * DH + fq * 8];
  const short8 aq1 = *(const short8*)&Qb[(size_t)(i0w + fr) * DH + 32 + fq * 8];

  float mrow[4], lp[4];
  f32x4 accO[4];
#pragma unroll
  for (int r = 0; r < 4; r++) { mrow[r] = -3.0e38f; lp[r] = 0.f; }
#pragma unroll
  for (int t = 0; t < 4; t++) accO[t] = fzero;

  f32x4 zzc = fzero;  // carried Er band fragment (prev f=4 -> next f=0)
  const int ksw = (fr & 7) << 4;

  // prologue: iter-0 K/V + full 192-row Er window
  int buf = 0;
  stageKV(0, 0);
  stageEl(E0b, 3);
  __syncthreads();

  for (int j0 = 0; j0 <= jmax; j0 += 64) {
    // ---- prefetch for iter j0+64 (disjoint LDS: buf^1 + ring slots)
    if (j0 < jmax) {
      stageKV(j0 + 64, buf ^ 1);
      stageEl(E0b + j0 + 192, 1);
    }

    // wave-uniform: highest unmasked t-subtile (neg => this wave idle)
    int tmax = (i0w + 15 - j0) >> 4;
    if (tmax > 3) tmax = 3;

    if (tmax >= 0) {
      // ---- S = Q K^T from swizzled LDS
      f32x4 sfr[4];
#pragma unroll
      for (int t = 0; t < 4; t++) sfr[t] = fzero;
      __builtin_amdgcn_s_setprio(1);
#pragma unroll
      for (int t = 0; t < 4; t++)
        if (t <= tmax) {
          const char* kr = (const char*)&Kl[buf][0] + (t * 16 + fr) * 128;
          const short8 b0 = *(const short8*)(kr + ((fq * 16) ^ ksw));
          const short8 b1 = *(const short8*)(kr + ((64 + fq * 16) ^ ksw));
          f32x4 z = fzero;
          z = __builtin_amdgcn_mfma_f32_16x16x32_bf16(aq0, b0, z, 0, 0, 0);
          z = __builtin_amdgcn_mfma_f32_16x16x32_bf16(aq1, b1, z, 0, 0, 0);
          sfr[t] = z;
        }
      __builtin_amdgcn_s_setprio(0);

      // ---- banded QEr from the ring; f=0 carried when j0>0
      const int ebs = S_LEN - 16 - i0w + j0;  // band base (mult of 16)
      f32x4 zz[5];
#pragma unroll
      for (int f = 0; f < 5; f++) zz[f] = fzero;
      const int f0 = (j0 == 0) ? 0 : 1;
#pragma unroll
      for (int f = 0; f < 5; f++)
        if (f >= f0 && f <= tmax + 1) {
          const int slot = ((ebs + f * 16) & 255) + fr;  // no straddle
          const char* er = (const char*)El + slot * 128;
          const short8 b0 = *(const short8*)(er + ((fq * 16) ^ ksw));
          const short8 b1 = *(const short8*)(er + ((64 + fq * 16) ^ ksw));
          f32x4 z = fzero;
          z = __builtin_amdgcn_mfma_f32_16x16x32_bf16(aq0, b0, z, 0, 0, 0);
          z = __builtin_amdgcn_mfma_f32_16x16x32_bf16(aq1, b1, z, 0, 0, 0);
          zz[f] = z;
        }
      if (j0 > 0) zz[0] = zzc;
      zzc = zz[4];

      // ---- in-register skew gather: rel[t][r] = band col (15-row+fr)+16t
      float p[4][4];
#pragma unroll
      for (int r = 0; r < 4; r++) {
        const int row = fq * 4 + r;
        const int c = 15 - row + fr;           // 0..30
        const int src = (fq << 4) | (c & 15);  // same row-group, lane c&15
        float sh[5];
#pragma unroll
        for (int f = 0; f < 5; f++) sh[f] = __shfl(zz[f][r], src);
#pragma unroll
        for (int t = 0; t < 4; t++) {
          const float rel = (c < 16) ? sh[t] : sh[t + 1];
          float sv = (sfr[t][r] + rel) * 0.125f;
          const int jj = j0 + t * 16 + fr;
          const int ii = i0w + row;
          if (jj > ii) sv = -3.0e38f;
          p[t][r] = sv;
        }
      }

      // ---- online softmax (DPP max; lrow kept as per-lane partials)
#pragma unroll
      for (int r = 0; r < 4; r++) {
        float rm = fmaxf(fmaxf(p[0][r], p[1][r]), fmaxf(p[2][r], p[3][r]));
        rm = grp16_max(rm);
        const float mnew = fmaxf(mrow[r], rm);
        const float alpha = __expf(mrow[r] - mnew);
        mrow[r] = mnew;
        float rs = 0.f;
#pragma unroll
        for (int t = 0; t < 4; t++) {
          const float e = __expf(p[t][r] - mnew);
          p[t][r] = e;
          rs += e;
        }
        lp[r] = lp[r] * alpha + rs;  // allreduce deferred to epilogue
#pragma unroll
        for (int t = 0; t < 4; t++) accO[t][r] *= alpha;
      }

      // ---- P transpose, wave-private, XOR-swizzled (stride 64 u16)
#pragma unroll
      for (int t = 0; t < 4; t++)
#pragma unroll
        for (int r = 0; r < 4; r++)
          Pw[(fq * 4 + r) * 64 + (((t ^ fq) << 4) + fr)] = f2bf(p[t][r]);
      __builtin_amdgcn_s_waitcnt(0xC07F);  // lgkmcnt(0): own writes visible

      const int rsw = (fr >> 2) << 4;
      const short8 ap0 = *(const short8*)&Pw[fr * 64 + ((fq * 8) ^ rsw)];
      const short8 ap1 = *(const short8*)&Pw[fr * 64 + ((32 + fq * 8) ^ rsw)];

      // ---- O += P V from swizzled LDS
      __builtin_amdgcn_s_setprio(1);
#pragma unroll
      for (int t = 0; t < 4; t++) {
        const char* vr = (const char*)&Vl[buf][0] + (t * 16 + fr) * 128;
        const short8 b0 = *(const short8*)(vr + ((fq * 16) ^ ksw));
        const short8 b1 = *(const short8*)(vr + ((64 + fq * 16) ^ ksw));
        accO[t] =
            __builtin_amdgcn_mfma_f32_16x16x32_bf16(ap0, b0, accO[t], 0, 0, 0);
        accO[t] =
            __builtin_amdgcn_mfma_f32_16x16x32_bf16(ap1, b1, accO[t], 0, 0, 0);
      }
      __builtin_amdgcn_s_setprio(0);
    }

    __syncthreads();  // drains prefetch (vmcnt) + guards buffer/ring reuse
    buf ^= 1;
  }

  // ---- epilogue: one deferred lrow allreduce, then O / l, write fp32
#pragma unroll
  for (int r = 0; r < 4; r++) {
    const float lr = grp16_sum(lp[r]);
    const float inv = 1.f / lr;
    const int s = i0w + fq * 4 + r;
#pragma unroll
    for (int t = 0; t < 4; t++) {
      const int d = t * 16 + fr;
      out[((size_t)b * S_LEN + s) * DM + h * DH + d] = accO[t][r] * inv;
    }
  }
}

extern "C" void kernel_launch(void* const* d_in, const int* in_sizes, int n_in,
                              void* d_out, int out_size, void* d_ws, size_t ws_size,
                              hipStream_t stream) {
  const float* x = (const float*)d_in[0];
  const float* Wq = (const float*)d_in[1];
  const float* bq = (const float*)d_in[2];
  const float* Wk = (const float*)d_in[3];
  const float* bk = (const float*)d_in[4];
  const float* Wv = (const float*)d_in[5];
  const float* bv = (const float*)d_in[6];
  const float* Er = (const float*)d_in[7];
  float* out = (float*)d_out;

  const size_t per = (size_t)NB * NH * S_LEN * DH;  // 4M elems
  u16* Qw = (u16*)d_ws;
  u16* Kw = Qw + per;
  u16* Vw = Kw + per;
  u16* xb = Vw + per;
  u16* Wqb = xb + per;
  u16* Wkb = Wqb + (size_t)DM * DM;
  u16* Wvb = Wkb + (size_t)DM * DM;
  u16* Erb = Wvb + (size_t)DM * DM;

  cvt_f32_bf16<<<3616, 256, 0, stream>>>(x, Wq, Wk, Wv, Er, xb, Wqb, Wkb, Wvb,
                                         Erb);
  dim3 g1(DM / 128, (NB * S_LEN) / 128, 3);
  qkv_gemm<<<g1, dim3(256), 0, stream>>>(xb, Wqb, bq, Wkb, bk, Wvb, bv, Qw, Kw,
                                         Vw);
  dim3 g2(8, NB * NH);
  attn<<<g2, dim3(512), 0, stream>>>(Qw, Kw, Vw, Erb, out);
}

// Round 9
// 161.367 us; speedup vs baseline: 1.4318x; 1.0892x over previous
//
#include <hip/hip_runtime.h>
#include <stdint.h>

#define S_LEN 1024
#define DM 1024
#define NH 16
#define DH 64
#define NB 4

typedef unsigned short u16;
typedef __attribute__((ext_vector_type(8))) short short8;
typedef __attribute__((ext_vector_type(4))) float f32x4;
typedef __attribute__((ext_vector_type(4))) unsigned int u32x4;
typedef __attribute__((ext_vector_type(4))) unsigned short u16x4;

__device__ __forceinline__ u16 f2bf(float f) {
  union { float f; unsigned int u; } c;
  c.f = f;
  unsigned int u = c.u;
  return (u16)((u + 0x7fffu + ((u >> 16) & 1u)) >> 16);
}

// async global->LDS, 16B per lane. LDS dest must be wave-uniform-base + lane*16.
__device__ __forceinline__ void g2l16(const void* g, void* l) {
  __builtin_amdgcn_global_load_lds(
      (const __attribute__((address_space(1))) unsigned int*)(uintptr_t)g,
      (__attribute__((address_space(3))) unsigned int*)(uint32_t)(uintptr_t)l,
      16, 0, 0);
}

// 16-lane-group allreduce on the VALU pipe (DPP): quad_perm xor1, xor2,
// row_ror:4, row_ror:8. Rotate-allreduce; exec must be wave-uniform.
__device__ __forceinline__ float grp16_max(float v) {
  union { float f; int i; } c, o;
  c.f = v; o.i = __builtin_amdgcn_update_dpp(c.i, c.i, 0xB1, 0xF, 0xF, false);
  v = fmaxf(v, o.f);
  c.f = v; o.i = __builtin_amdgcn_update_dpp(c.i, c.i, 0x4E, 0xF, 0xF, false);
  v = fmaxf(v, o.f);
  c.f = v; o.i = __builtin_amdgcn_update_dpp(c.i, c.i, 0x124, 0xF, 0xF, false);
  v = fmaxf(v, o.f);
  c.f = v; o.i = __builtin_amdgcn_update_dpp(c.i, c.i, 0x128, 0xF, 0xF, false);
  v = fmaxf(v, o.f);
  return v;
}
__device__ __forceinline__ float grp16_sum(float v) {
  union { float f; int i; } c, o;
  c.f = v; o.i = __builtin_amdgcn_update_dpp(c.i, c.i, 0xB1, 0xF, 0xF, false);
  v += o.f;
  c.f = v; o.i = __builtin_amdgcn_update_dpp(c.i, c.i, 0x4E, 0xF, 0xF, false);
  v += o.f;
  c.f = v; o.i = __builtin_amdgcn_update_dpp(c.i, c.i, 0x124, 0xF, 0xF, false);
  v += o.f;
  c.f = v; o.i = __builtin_amdgcn_update_dpp(c.i, c.i, 0x128, 0xF, 0xF, false);
  v += o.f;
  return v;
}

// ---------------------------------------------------------------------------
// Kernel 0: fp32 -> bf16 pre-convert of x, Wq, Wk, Wv, Er into workspace.
// ---------------------------------------------------------------------------
__global__ __launch_bounds__(256) void cvt_f32_bf16(
    const float* __restrict__ x, const float* __restrict__ Wq,
    const float* __restrict__ Wk, const float* __restrict__ Wv,
    const float* __restrict__ Er, u16* __restrict__ xb,
    u16* __restrict__ Wqb, u16* __restrict__ Wkb, u16* __restrict__ Wvb,
    u16* __restrict__ Erb) {
  const size_t f = ((size_t)blockIdx.x * 256 + threadIdx.x) * 8;
  const float* src;
  u16* dst;
  size_t off;
  if (f < 4194304) { src = x; dst = xb; off = f; }
  else if (f < 5242880) { src = Wq; dst = Wqb; off = f - 4194304; }
  else if (f < 6291456) { src = Wk; dst = Wkb; off = f - 5242880; }
  else if (f < 7340032) { src = Wv; dst = Wvb; off = f - 6291456; }
  else { src = Er; dst = Erb; off = f - 7340032; }
  const float4 a = *(const float4*)(src + off);
  const float4 b = *(const float4*)(src + off + 4);
  u16 o[8] = {f2bf(a.x), f2bf(a.y), f2bf(a.z), f2bf(a.w),
              f2bf(b.x), f2bf(b.y), f2bf(b.z), f2bf(b.w)};
  *(u32x4*)(dst + off) = *(const u32x4*)o;
}

// ---------------------------------------------------------------------------
// Kernel 1: fused QKV projection. r8 structure (XCD-chunked remap, verified
// FETCH 68.7->29.8MB) + ONE change: 1-barrier double-buffered staging.
// Prefetch k+32 into buf^1 at the top of iter k; the single end-of-iter
// __syncthreads' implicit vmcnt(0) drains loads issued ~600cy earlier
// (hidden under 16 MFMA + frag reads) -- the r8-attn-proven pattern.
// ---------------------------------------------------------------------------
__global__ __launch_bounds__(256) void qkv_gemm(
    const u16* __restrict__ x,
    const u16* __restrict__ Wq, const float* __restrict__ bq,
    const u16* __restrict__ Wk, const float* __restrict__ bk,
    const u16* __restrict__ Wv, const float* __restrict__ bv,
    u16* __restrict__ Qo, u16* __restrict__ Ko, u16* __restrict__ Vo) {
  __shared__ __attribute__((aligned(16))) u16 Al[2][128 * 32];
  __shared__ __attribute__((aligned(16))) u16 Bl[2][128 * 32];

  const int tid = threadIdx.x;
  const int lane = tid & 63;
  const int wave = tid >> 6;

  // ---- XCD-chunked remap (768 blocks, 768%8==0 -> simple bijection)
  const int o =
      ((int)blockIdx.z * gridDim.y + blockIdx.y) * gridDim.x + blockIdx.x;
  const int swz = (o & 7) * 96 + (o >> 3);
  const int z = swz >> 8;           // 0..2
  const int rem = swz & 255;
  const int m0 = (rem >> 3) * 128;  // 32 m-tiles
  const int n0 = (rem & 7) * 128;   // 8 n-tiles

  const u16* W = (z == 0) ? Wq : (z == 1) ? Wk : Wv;
  const float* bias = (z == 0) ? bq : (z == 1) ? bk : bv;

  f32x4 acc[4][4];
  const f32x4 fzero = {0.f, 0.f, 0.f, 0.f};
#pragma unroll
  for (int i = 0; i < 4; i++)
#pragma unroll
    for (int j = 0; j < 4; j++) acc[i][j] = fzero;

  const int srow = tid >> 2;
  const int schunk = tid & 3;
  const u16* gA = x + (size_t)(m0 + srow) * DM + schunk * 8;
  const u16* gB = W + (size_t)(n0 + srow) * DM + schunk * 8;

  const int fr = lane & 15;
  const int fq = lane >> 4;
  const int wr = (wave >> 1) * 64;
  const int wc = (wave & 1) * 64;

  auto stageAB = [&](int k, int bf) {
    g2l16(gA + k, &Al[bf][tid * 8]);
    g2l16(gA + (size_t)64 * DM + k, &Al[bf][2048 + tid * 8]);
    g2l16(gB + k, &Bl[bf][tid * 8]);
    g2l16(gB + (size_t)64 * DM + k, &Bl[bf][2048 + tid * 8]);
  };

  stageAB(0, 0);
  __syncthreads();
  int bf = 0;

  for (int k = 0; k < DM; k += 32) {
    if (k + 32 < DM) stageAB(k + 32, bf ^ 1);  // prefetch next K-step
    short8 a[4], b[4];
#pragma unroll
    for (int i = 0; i < 4; i++)
      a[i] = *(const short8*)&Al[bf][(wr + i * 16 + fr) * 32 + fq * 8];
#pragma unroll
    for (int j = 0; j < 4; j++)
      b[j] = *(const short8*)&Bl[bf][(wc + j * 16 + fr) * 32 + fq * 8];
    __builtin_amdgcn_s_setprio(1);
#pragma unroll
    for (int i = 0; i < 4; i++)
#pragma unroll
      for (int j = 0; j < 4; j++)
        acc[i][j] =
            __builtin_amdgcn_mfma_f32_16x16x32_bf16(a[i], b[j], acc[i][j], 0, 0, 0);
    __builtin_amdgcn_s_setprio(0);
    __syncthreads();  // drains prefetch (vmcnt0) + guards buffer reuse
    bf ^= 1;
  }

#pragma unroll
  for (int j = 0; j < 4; j++) {
    const int n = n0 + wc + j * 16 + fr;
    const float bsv = bias[n];
    const int h = n >> 6, d = n & (DH - 1);
#pragma unroll
    for (int i = 0; i < 4; i++) {
      const int mb = m0 + wr + i * 16 + fq * 4;
      const int bb = mb >> 10, s = mb & (S_LEN - 1);
      if (z == 2) {
        // 4 consecutive s -> one 8B store into V^T
        u16x4 ov;
#pragma unroll
        for (int r = 0; r < 4; r++) ov[r] = f2bf(acc[i][j][r] + bsv);
        *(u16x4*)&Vo[((size_t)(bb * NH + h) * DH + d) * S_LEN + s] = ov;
      } else if (z == 1) {
#pragma unroll
        for (int r = 0; r < 4; r++)
          Ko[((size_t)(bb * NH + h) * S_LEN + s + r) * DH + d] =
              f2bf(acc[i][j][r] + bsv);
      } else {
#pragma unroll
        for (int r = 0; r < 4; r++)
          Qo[((size_t)(bb * NH + h) * S_LEN + s + r) * DH + d] =
              f2bf(acc[i][j][r] + bsv);
      }
    }
  }
}

// ---------------------------------------------------------------------------
// Kernel 2: causal flash attention with relative-position (skew) bias.
// r8 pipelined 8-wave structure (K/V dbuf + 256-row El ring, 1 barrier/iter)
// + index remap only:
//  - XCD grouping: bh = blockIdx.x*8 + (y&7). Grid (8,64) flattens to
//    o = y*8+x, XCD = o&7 = x -> all 8 blocks of one bh now land on ONE XCD
//    (previously 8 different XCDs each re-fetching that bh's K/V).
//  - CU-pair balance: slot = y>>3; it = slot<4 ? slot : 11-slot. A CU hosting
//    blocks (j, j+32) gets i-tile pairs (it, 7-it) -> always 18 iters total
//    (was 12..24, a 33% tail with full residency and no backfill).
// ---------------------------------------------------------------------------
__global__ __launch_bounds__(512, 4) void attn(
    const u16* __restrict__ Q, const u16* __restrict__ K,
    const u16* __restrict__ Vt, const u16* __restrict__ Er,
    float* __restrict__ out) {
  __shared__ __attribute__((aligned(16))) u16 Kl[2][64 * 64];  // 16KB
  __shared__ __attribute__((aligned(16))) u16 Vl[2][64 * 64];  // 16KB
  __shared__ __attribute__((aligned(16))) u16 El[256 * 64];    // 32KB ring
  __shared__ __attribute__((aligned(16))) u16 Pl[8][16 * 64];  // 16KB

  const int tid = threadIdx.x;
  const int lane = tid & 63;
  const int w = tid >> 6;  // wave 0..7
  // XCD-grouped remap: bh's 8 blocks all on XCD (o&7)=blockIdx.x
  const int bh = (int)blockIdx.x * 8 + ((int)blockIdx.y & 7);
  const int slot = (int)blockIdx.y >> 3;               // 0..7
  const int it = (slot < 4) ? slot : 11 - slot;        // CU-pair sum uniform
  const int b = bh >> 4, h = bh & (NH - 1);
  const int i0 = it * 128;
  const int jmax = i0 + 64;
  const int i0w = i0 + w * 16;       // this wave's 16 q-rows
  const int E0b = S_LEN - 128 - i0;  // Er window base at j0=0 (>=0, mult 64)

  const u16* Qb = Q + (size_t)bh * S_LEN * DH;
  const char* Kb = (const char*)(K + (size_t)bh * S_LEN * DH);
  const char* Vb = (const char*)(Vt + (size_t)bh * DH * S_LEN);
  const char* Eb = (const char*)Er;
  u16* Pw = Pl[w];

  const int fr = lane & 15;
  const int fq = lane >> 4;
  const f32x4 fzero = {0.f, 0.f, 0.f, 0.f};

  // staging: 512 threads cover 64 rows x 128B per pass
  const int r0 = tid >> 3;        // row 0..63
  const int ch = (tid & 7) * 16;  // byte chunk within 128B row

  auto stageKV = [&](int j0, int bf) {
    const int sw = ch ^ ((r0 & 7) << 4);
    g2l16(Kb + (size_t)(j0 + r0) * 128 + sw, (char*)&Kl[bf][0] + r0 * 128 + ch);
    g2l16(Vb + (size_t)r0 * 2048 + j0 * 2 + sw,
          (char*)&Vl[bf][0] + r0 * 128 + ch);
  };
  // Er rows [e0, e0+64*np) into ring slots e&255 (e0 mult of 64 -> no
  // straddle; rows >1023 clamp, they only feed masked positions).
  auto stageEl = [&](int e0, int np) {
    for (int p = 0; p < np; p++) {
      const int e = e0 + p * 64 + r0;
      const int slt = e & 255;
      const int ec = (e > S_LEN - 1) ? (S_LEN - 1) : e;
      const int sw = ch ^ ((slt & 7) << 4);
      g2l16(Eb + (size_t)ec * 128 + sw, (char*)El + slt * 128 + ch);
    }
  };

  const short8 aq0 = *(const short8*)&Qb[(size_t)(i0w + fr) * DH + fq * 8];
  const short8 aq1 = *(const short8*)&Qb[(size_t)(i0w + fr) * DH + 32 + fq * 8];

  float mrow[4], lp[4];
  f32x4 accO[4];
#pragma unroll
  for (int r = 0; r < 4; r++) { mrow[r] = -3.0e38f; lp[r] = 0.f; }
#pragma unroll
  for (int t = 0; t < 4; t++) accO[t] = fzero;

  f32x4 zzc = fzero;  // carried Er band fragment (prev f=4 -> next f=0)
  const int ksw = (fr & 7) << 4;

  // prologue: iter-0 K/V + full 192-row Er window
  int buf = 0;
  stageKV(0, 0);
  stageEl(E0b, 3);
  __syncthreads();

  for (int j0 = 0; j0 <= jmax; j0 += 64) {
    // ---- prefetch for iter j0+64 (disjoint LDS: buf^1 + ring slots)
    if (j0 < jmax) {
      stageKV(j0 + 64, buf ^ 1);
      stageEl(E0b + j0 + 192, 1);
    }

    // wave-uniform: highest unmasked t-subtile (neg => this wave idle)
    int tmax = (i0w + 15 - j0) >> 4;
    if (tmax > 3) tmax = 3;

    if (tmax >= 0) {
      // ---- S = Q K^T from swizzled LDS
      f32x4 sfr[4];
#pragma unroll
      for (int t = 0; t < 4; t++) sfr[t] = fzero;
      __builtin_amdgcn_s_setprio(1);
#pragma unroll
      for (int t = 0; t < 4; t++)
        if (t <= tmax) {
          const char* kr = (const char*)&Kl[buf][0] + (t * 16 + fr) * 128;
          const short8 b0 = *(const short8*)(kr + ((fq * 16) ^ ksw));
          const short8 b1 = *(const short8*)(kr + ((64 + fq * 16) ^ ksw));
          f32x4 z = fzero;
          z = __builtin_amdgcn_mfma_f32_16x16x32_bf16(aq0, b0, z, 0, 0, 0);
          z = __builtin_amdgcn_mfma_f32_16x16x32_bf16(aq1, b1, z, 0, 0, 0);
          sfr[t] = z;
        }
      __builtin_amdgcn_s_setprio(0);

      // ---- banded QEr from the ring; f=0 carried when j0>0
      const int ebs = S_LEN - 16 - i0w + j0;  // band base (mult of 16)
      f32x4 zz[5];
#pragma unroll
      for (int f = 0; f < 5; f++) zz[f] = fzero;
      const int f0 = (j0 == 0) ? 0 : 1;
#pragma unroll
      for (int f = 0; f < 5; f++)
        if (f >= f0 && f <= tmax + 1) {
          const int slt = ((ebs + f * 16) & 255) + fr;  // no straddle
          const char* er = (const char*)El + slt * 128;
          const short8 b0 = *(const short8*)(er + ((fq * 16) ^ ksw));
          const short8 b1 = *(const short8*)(er + ((64 + fq * 16) ^ ksw));
          f32x4 z = fzero;
          z = __builtin_amdgcn_mfma_f32_16x16x32_bf16(aq0, b0, z, 0, 0, 0);
          z = __builtin_amdgcn_mfma_f32_16x16x32_bf16(aq1, b1, z, 0, 0, 0);
          zz[f] = z;
        }
      if (j0 > 0) zz[0] = zzc;
      zzc = zz[4];

      // ---- in-register skew gather: rel[t][r] = band col (15-row+fr)+16t
      float p[4][4];
#pragma unroll
      for (int r = 0; r < 4; r++) {
        const int row = fq * 4 + r;
        const int c = 15 - row + fr;           // 0..30
        const int src = (fq << 4) | (c & 15);  // same row-group, lane c&15
        float sh[5];
#pragma unroll
        for (int f = 0; f < 5; f++) sh[f] = __shfl(zz[f][r], src);
#pragma unroll
        for (int t = 0; t < 4; t++) {
          const float rel = (c < 16) ? sh[t] : sh[t + 1];
          float sv = (sfr[t][r] + rel) * 0.125f;
          const int jj = j0 + t * 16 + fr;
          const int ii = i0w + row;
          if (jj > ii) sv = -3.0e38f;
          p[t][r] = sv;
        }
      }

      // ---- online softmax (DPP max; lrow kept as per-lane partials)
#pragma unroll
      for (int r = 0; r < 4; r++) {
        float rm = fmaxf(fmaxf(p[0][r], p[1][r]), fmaxf(p[2][r], p[3][r]));
        rm = grp16_max(rm);
        const float mnew = fmaxf(mrow[r], rm);
        const float alpha = __expf(mrow[r] - mnew);
        mrow[r] = mnew;
        float rs = 0.f;
#pragma unroll
        for (int t = 0; t < 4; t++) {
          const float e = __expf(p[t][r] - mnew);
          p[t][r] = e;
          rs += e;
        }
        lp[r] = lp[r] * alpha + rs;  // allreduce deferred to epilogue
#pragma unroll
        for (int t = 0; t < 4; t++) accO[t][r] *= alpha;
      }

      // ---- P transpose, wave-private, XOR-swizzled (stride 64 u16)
#pragma unroll
      for (int t = 0; t < 4; t++)
#pragma unroll
        for (int r = 0; r < 4; r++)
          Pw[(fq * 4 + r) * 64 + (((t ^ fq) << 4) + fr)] = f2bf(p[t][r]);
      __builtin_amdgcn_s_waitcnt(0xC07F);  // lgkmcnt(0): own writes visible

      const int rsw = (fr >> 2) << 4;
      const short8 ap0 = *(const short8*)&Pw[fr * 64 + ((fq * 8) ^ rsw)];
      const short8 ap1 = *(const short8*)&Pw[fr * 64 + ((32 + fq * 8) ^ rsw)];

      // ---- O += P V from swizzled LDS
      __builtin_amdgcn_s_setprio(1);
#pragma unroll
      for (int t = 0; t < 4; t++) {
        const char* vr = (const char*)&Vl[buf][0] + (t * 16 + fr) * 128;
        const short8 b0 = *(const short8*)(vr + ((fq * 16) ^ ksw));
        const short8 b1 = *(const short8*)(vr + ((64 + fq * 16) ^ ksw));
        accO[t] =
            __builtin_amdgcn_mfma_f32_16x16x32_bf16(ap0, b0, accO[t], 0, 0, 0);
        accO[t] =
            __builtin_amdgcn_mfma_f32_16x16x32_bf16(ap1, b1, accO[t], 0, 0, 0);
      }
      __builtin_amdgcn_s_setprio(0);
    }

    __syncthreads();  // drains prefetch (vmcnt) + guards buffer/ring reuse
    buf ^= 1;
  }

  // ---- epilogue: one deferred lrow allreduce, then O / l, write fp32
#pragma unroll
  for (int r = 0; r < 4; r++) {
    const float lr = grp16_sum(lp[r]);
    const float inv = 1.f / lr;
    const int s = i0w + fq * 4 + r;
#pragma unroll
    for (int t = 0; t < 4; t++) {
      const int d = t * 16 + fr;
      out[((size_t)b * S_LEN + s) * DM + h * DH + d] = accO[t][r] * inv;
    }
  }
}

extern "C" void kernel_launch(void* const* d_in, const int* in_sizes, int n_in,
                              void* d_out, int out_size, void* d_ws, size_t ws_size,
                              hipStream_t stream) {
  const float* x = (const float*)d_in[0];
  const float* Wq = (const float*)d_in[1];
  const float* bq = (const float*)d_in[2];
  const float* Wk = (const float*)d_in[3];
  const float* bk = (const float*)d_in[4];
  const float* Wv = (const float*)d_in[5];
  const float* bv = (const float*)d_in[6];
  const float* Er = (const float*)d_in[7];
  float* out = (float*)d_out;

  const size_t per = (size_t)NB * NH * S_LEN * DH;  // 4M elems
  u16* Qw = (u16*)d_ws;
  u16* Kw = Qw + per;
  u16* Vw = Kw + per;
  u16* xb = Vw + per;
  u16* Wqb = xb + per;
  u16* Wkb = Wqb + (size_t)DM * DM;
  u16* Wvb = Wkb + (size_t)DM * DM;
  u16* Erb = Wvb + (size_t)DM * DM;

  cvt_f32_bf16<<<3616, 256, 0, stream>>>(x, Wq, Wk, Wv, Er, xb, Wqb, Wkb, Wvb,
                                         Erb);
  dim3 g1(DM / 128, (NB * S_LEN) / 128, 3);
  qkv_gemm<<<g1, dim3(256), 0, stream>>>(xb, Wqb, bq, Wkb, bk, Wvb, bv, Qw, Kw,
                                         Vw);
  dim3 g2(8, NB * NH);
  attn<<<g2, dim3(512), 0, stream>>>(Qw, Kw, Vw, Erb, out);
}